// Round 4
// baseline (4172.208 us; speedup 1.0000x reference)
//
#include <hip/hip_runtime.h>
#include <hip/hip_fp16.h>

#define B 16
#define NN 200000
#define R 1000000
#define ITERS 5
#define NBUCK 3125            // NN / 64
#define BS 64                 // nodes per bucket
#define CAP 3584              // entry capacity per bucket (mean 2560, sigma ~51)

typedef unsigned int uint;
typedef unsigned short ushort;

__device__ __forceinline__ float sigmoidf_(float x) {
    return 1.0f / (1.0f + __expf(-x));
}

// ---------------- build phase (bucket scatter, no count/scan) ----------------

__global__ void cavi_zero_cur(uint* __restrict__ cur) {
    int i = blockIdx.x * blockDim.x + threadIdx.x;
    if (i < NBUCK * 16) cur[i] = 0u;
}

// Entry (8B): lo = s1(0..17) | md1(18..19) | s2_lo12(20..31)
//             hi = s2_hi6(0..5) | md2(6..7) | ldest(8..13) | fp16 w(16..31)
// mods: 0 -> x, 1 -> x-1, 2 -> 1-x, 3 -> constant 1
__device__ __forceinline__ void put_entry(int dest, int s1, uint md1, int s2, uint md2,
                                          uint hw, uint* __restrict__ cursor,
                                          uint2* __restrict__ ent) {
    uint bk = (uint)dest >> 6;
    uint ld = (uint)dest & 63u;
    uint pos = atomicAdd(&cursor[bk * 16], 1u);
    if (pos < CAP) {
        uint lo = (uint)s1 | (md1 << 18) | (((uint)s2 & 0xFFFu) << 20);
        uint hi = ((uint)s2 >> 12) | (md2 << 6) | (ld << 8) | (hw << 16);
        ent[(size_t)bk * CAP + pos] = make_uint2(lo, hi);
    }
}

__global__ void cavi_fill_bkt(const int* __restrict__ i1, const float* __restrict__ w1,
                              const int* __restrict__ i2, const float* __restrict__ w2,
                              const int* __restrict__ i3, const float* __restrict__ w3,
                              uint* __restrict__ cursor, uint2* __restrict__ ent) {
    int e = blockIdx.x * blockDim.x + threadIdx.x;
    if (e >= R) return;
    {   // t1: delta[c] += w*qa ; delta[a] += w*(qc-1)
        int a = i1[2 * e], c = i1[2 * e + 1];
        uint hw = (uint)__half_as_ushort(__float2half(w1[e]));
        put_entry(c, a, 0u, 0, 3u, hw, cursor, ent);
        put_entry(a, c, 1u, 0, 3u, hw, cursor, ent);
    }
    {   // t2: delta[c] += w*qa*qb ; delta[a] += w*qb*(qc-1) ; delta[b] += w*qa*(qc-1)
        int a = i2[3 * e], b = i2[3 * e + 1], c = i2[3 * e + 2];
        uint hw = (uint)__half_as_ushort(__float2half(w2[e]));
        put_entry(c, a, 0u, b, 0u, hw, cursor, ent);
        put_entry(a, b, 0u, c, 1u, hw, cursor, ent);
        put_entry(b, a, 0u, c, 1u, hw, cursor, ent);
    }
    {   // t3: delta[c] += w*qa*(1-qb) ; delta[a] += w*(1-qb)*(qc-1) ; delta[b] += w*qa*(1-qc)
        int a = i3[3 * e], b = i3[3 * e + 1], c = i3[3 * e + 2];
        uint hw = (uint)__half_as_ushort(__float2half(w3[e]));
        put_entry(c, a, 0u, b, 2u, hw, cursor, ent);
        put_entry(a, b, 2u, c, 1u, hw, cursor, ent);
        put_entry(b, a, 0u, c, 2u, hw, cursor, ent);
    }
}

// ---------------- init / finish transposes ----------------

// ev [B][N] -> ev_nb [N][B] (f32); logits_nb = ev_nb (f32); q0 = sigmoid(ev) (fp16)
__global__ void cavi_init_tp(const float* __restrict__ ev, float* __restrict__ ev_nb,
                             float* __restrict__ logits_nb, __half* __restrict__ q0) {
    __shared__ float lds[64 * 17];
    int n0 = blockIdx.x * 64;   // NN % 64 == 0
    #pragma unroll
    for (int p = 0; p < 4; ++p) {
        int idx = p * 256 + threadIdx.x;     // b-major
        int b = idx >> 6, i = idx & 63;
        lds[i * 17 + b] = ev[b * NN + n0 + i];
    }
    __syncthreads();
    #pragma unroll
    for (int p = 0; p < 4; ++p) {
        int j = p * 256 + threadIdx.x;       // j = i*16 + b
        int i = j >> 4, b = j & 15;
        float v = lds[i * 17 + b];
        int o = n0 * B + j;
        ev_nb[o] = v;
        logits_nb[o] = v;
        q0[o] = __float2half(sigmoidf_(v));
    }
}

// q_nb [N][B] fp16 -> out [B][N] f32
__global__ void cavi_out_tp(const __half* __restrict__ q_nb, float* __restrict__ out) {
    __shared__ float lds[64 * 17];
    int n0 = blockIdx.x * 64;
    #pragma unroll
    for (int p = 0; p < 4; ++p) {
        int j = p * 256 + threadIdx.x;       // j = i*16 + b
        int i = j >> 4, b = j & 15;
        lds[i * 17 + b] = __half2float(q_nb[n0 * B + j]);
    }
    __syncthreads();
    #pragma unroll
    for (int p = 0; p < 4; ++p) {
        int idx = p * 256 + threadIdx.x;     // b-major
        int b = idx >> 6, i = idx & 63;
        out[b * NN + n0 + i] = lds[i * 17 + b];
    }
}

// ---------------- main fused iteration (block per bucket, LDS reduction) ----------------

__global__ __launch_bounds__(256) void cavi_main_bkt(
        const uint* __restrict__ cursor, const uint2* __restrict__ ent,
        const float* __restrict__ ev_nb, float* __restrict__ logits_nb,
        const __half* __restrict__ q_in, __half* __restrict__ q_out) {
    __shared__ float dlt[BS * 16];          // 4 KB
    int tid = threadIdx.x;
    #pragma unroll
    for (int i = tid; i < BS * 16; i += 256) dlt[i] = 0.0f;
    __syncthreads();

    uint bk = blockIdx.x;
    uint cnt = cursor[bk * 16];
    if (cnt > CAP) cnt = CAP;
    const uint2* eb = ent + (size_t)bk * CAP;

    int b = tid & 15, g = tid >> 4;         // 16 entry-groups of 16 lanes
    for (uint k = (uint)g; k < cnt; k += 16) {
        uint2 e = eb[k];
        int s1 = (int)(e.x & 0x3FFFFu);
        uint md1 = (e.x >> 18) & 3u;
        int s2 = (int)(((e.x >> 20) & 0xFFFu) | ((e.y & 0x3Fu) << 12));
        uint md2 = (e.y >> 6) & 3u;
        int ld = (int)((e.y >> 8) & 0x3Fu);
        float w = __half2float(__ushort_as_half((ushort)(e.y >> 16)));
        float x = __half2float(q_in[(s1 << 4) + b]);
        x = (md1 == 0u) ? x : ((md1 == 1u) ? x - 1.0f : 1.0f - x);
        float q2 = __half2float(q_in[(s2 << 4) + b]);   // s2==0 for t1, harmless
        float y = (md2 == 0u) ? q2 : ((md2 == 1u) ? q2 - 1.0f : ((md2 == 2u) ? 1.0f - q2 : 1.0f));
        atomicAdd(&dlt[(ld << 4) + b], w * x * y);      // ds_add_f32
    }
    __syncthreads();

    int t0 = (int)bk * (BS * 16);
    #pragma unroll
    for (int i = tid; i < BS * 16; i += 256) {
        int t = t0 + i;
        float nl = 0.5f * logits_nb[t] + 0.5f * (ev_nb[t] + dlt[i]);
        logits_nb[t] = nl;
        q_out[t] = __float2half(sigmoidf_(nl));
    }
}

// ---------------- fallback (round-1 atomic path) ----------------

__global__ void fb_init(const float* __restrict__ ev, float* __restrict__ logits,
                        float* __restrict__ q_nb, float* __restrict__ delta_nb) {
    int i = blockIdx.x * blockDim.x + threadIdx.x;
    if (i >= NN * B) return;
    int b = i & 15, n = i >> 4;
    float e = ev[b * NN + n];
    logits[b * NN + n] = e;
    q_nb[i] = sigmoidf_(e);
    delta_nb[i] = 0.0f;
}

__global__ void fb_edges(const float* __restrict__ q, float* __restrict__ delta,
                         const int* __restrict__ idx1, const float* __restrict__ w1,
                         const int* __restrict__ idx2, const float* __restrict__ w2,
                         const int* __restrict__ idx3, const float* __restrict__ w3) {
    int gid = blockIdx.x * blockDim.x + threadIdx.x;
    int b = gid & 15;
    int e = gid >> 4;
    if (e >= 3 * R) return;
    if (e < R) {
        int a = idx1[e * 2 + 0], c = idx1[e * 2 + 1];
        float w = w1[e];
        float qa = q[a * B + b], qc = q[c * B + b];
        atomicAdd(&delta[c * B + b], w * qa);
        atomicAdd(&delta[a * B + b], w * (qc - 1.0f));
    } else if (e < 2 * R) {
        int ei = e - R;
        int a = idx2[ei * 3], bb = idx2[ei * 3 + 1], c = idx2[ei * 3 + 2];
        float w = w2[ei];
        float qa = q[a * B + b], qb = q[bb * B + b], qc = q[c * B + b];
        atomicAdd(&delta[c * B + b], w * qa * qb);
        atomicAdd(&delta[a * B + b], w * qb * (qc - 1.0f));
        atomicAdd(&delta[bb * B + b], w * qa * (qc - 1.0f));
    } else {
        int ei = e - 2 * R;
        int a = idx3[ei * 3], bb = idx3[ei * 3 + 1], c = idx3[ei * 3 + 2];
        float w = w3[ei];
        float qa = q[a * B + b], qb = q[bb * B + b], qc = q[c * B + b];
        atomicAdd(&delta[c * B + b], w * qa * (1.0f - qb));
        atomicAdd(&delta[a * B + b], w * (1.0f - qb) * (qc - 1.0f));
        atomicAdd(&delta[bb * B + b], w * qa * (1.0f - qc));
    }
}

__global__ void fb_update(const float* __restrict__ ev, float* __restrict__ logits,
                          float* __restrict__ q_nb, float* __restrict__ delta_nb, int write_q) {
    int i = blockIdx.x * blockDim.x + threadIdx.x;
    if (i >= NN * B) return;
    int b = i & 15, n = i >> 4;
    float d = delta_nb[i];
    delta_nb[i] = 0.0f;
    float e = ev[b * NN + n];
    float cl = logits[b * NN + n];
    float nl = 0.5f * cl + 0.5f * (e + d);
    float qv = sigmoidf_(nl);
    q_nb[i] = qv;
    logits[b * NN + n] = write_q ? qv : nl;
}

// ---------------- launch ----------------

extern "C" void kernel_launch(void* const* d_in, const int* in_sizes, int n_in,
                              void* d_out, int out_size, void* d_ws, size_t ws_size,
                              hipStream_t stream) {
    const float* ev = (const float*)d_in[0];
    const float* w1 = (const float*)d_in[1];
    const float* w2 = (const float*)d_in[2];
    const float* w3 = (const float*)d_in[3];
    const int* i1 = (const int*)d_in[4];
    const int* i2 = (const int*)d_in[5];
    const int* i3 = (const int*)d_in[6];

    const size_t NB = (size_t)NN * B;

    // workspace layout
    uint2* ent = (uint2*)d_ws;                           // NBUCK*CAP*8 = 89.6 MB
    float* ev_nb = (float*)(ent + (size_t)NBUCK * CAP);  // 12.8 MB
    float* logits_nb = ev_nb + NB;                       // 12.8 MB
    __half* q0 = (__half*)(logits_nb + NB);              // 6.4 MB
    __half* q1 = q0 + NB;                                // 6.4 MB
    uint* cursor = (uint*)(q1 + NB);                     // NBUCK*16 u32 = 200 KB
    size_t needed = (size_t)((char*)(cursor + NBUCK * 16) - (char*)d_ws);

    if (ws_size < needed) {
        // fallback: atomic path (needs 2*NB floats)
        float* logits = (float*)d_out;
        float* q_nb = (float*)d_ws;
        float* delta_nb = q_nb + NB;
        const int th = 256;
        const int nbg = (int)((NB + th - 1) / th);
        const int eg = (3 * R * B + th - 1) / th;
        fb_init<<<nbg, th, 0, stream>>>(ev, logits, q_nb, delta_nb);
        for (int it = 0; it < ITERS; ++it) {
            fb_edges<<<eg, th, 0, stream>>>(q_nb, delta_nb, i1, w1, i2, w2, i3, w3);
            fb_update<<<nbg, th, 0, stream>>>(ev, logits, q_nb, delta_nb, it == ITERS - 1 ? 1 : 0);
        }
        return;
    }

    const int th = 256;

    cavi_zero_cur<<<(NBUCK * 16 + th - 1) / th, th, 0, stream>>>(cursor);
    cavi_fill_bkt<<<(R + th - 1) / th, th, 0, stream>>>(i1, w1, i2, w2, i3, w3, cursor, ent);
    cavi_init_tp<<<NN / 64, 256, 0, stream>>>(ev, ev_nb, logits_nb, q0);

    __half* qi = q0;
    __half* qo = q1;
    for (int it = 0; it < ITERS; ++it) {
        cavi_main_bkt<<<NBUCK, 256, 0, stream>>>(cursor, ent, ev_nb, logits_nb, qi, qo);
        __half* tmp = qi; qi = qo; qo = tmp;
    }

    cavi_out_tp<<<NN / 64, 256, 0, stream>>>(qi, (float*)d_out);
}

// Round 5
// 4035.910 us; speedup vs baseline: 1.0338x; 1.0338x over previous
//
#include <hip/hip_runtime.h>
#include <hip/hip_fp16.h>

#define B 16
#define NN 200000
#define R 1000000
#define ITERS 5
#define NBUCK 3125            // NN / 64
#define BS 64                 // nodes per bucket
#define CAP 3584              // entry capacity per bucket (mean 2560, sigma ~51)

typedef unsigned int uint;
typedef unsigned short ushort;

__device__ __forceinline__ float sigmoidf_(float x) {
    return 1.0f / (1.0f + __expf(-x));
}

// ---------------- build phase (bucket scatter, no count/scan) ----------------

__global__ void cavi_zero_cur(uint* __restrict__ cur) {
    int i = blockIdx.x * blockDim.x + threadIdx.x;
    if (i < NBUCK * 16) cur[i] = 0u;
}

// Entry (8B): lo = s1(0..17) | md1(18..19) | s2_lo12(20..31)
//             hi = s2_hi6(0..5) | md2(6..7) | ldest(8..13) | fp16 w(16..31)
// mods: 0 -> x, 1 -> x-1, 2 -> 1-x, 3 -> constant 1
__device__ __forceinline__ void put_entry(int dest, int s1, uint md1, int s2, uint md2,
                                          uint hw, uint* __restrict__ cursor,
                                          uint2* __restrict__ ent) {
    uint bk = (uint)dest >> 6;
    uint ld = (uint)dest & 63u;
    uint pos = atomicAdd(&cursor[bk * 16], 1u);
    if (pos < CAP) {
        uint lo = (uint)s1 | (md1 << 18) | (((uint)s2 & 0xFFFu) << 20);
        uint hi = ((uint)s2 >> 12) | (md2 << 6) | (ld << 8) | (hw << 16);
        ent[(size_t)bk * CAP + pos] = make_uint2(lo, hi);
    }
}

__global__ void cavi_fill_bkt(const int* __restrict__ i1, const float* __restrict__ w1,
                              const int* __restrict__ i2, const float* __restrict__ w2,
                              const int* __restrict__ i3, const float* __restrict__ w3,
                              uint* __restrict__ cursor, uint2* __restrict__ ent) {
    int e = blockIdx.x * blockDim.x + threadIdx.x;
    if (e >= R) return;
    {   // t1: delta[c] += w*qa ; delta[a] += w*(qc-1)   (s2=s1 so the dead gather hits the same line)
        int a = i1[2 * e], c = i1[2 * e + 1];
        uint hw = (uint)__half_as_ushort(__float2half(w1[e]));
        put_entry(c, a, 0u, a, 3u, hw, cursor, ent);
        put_entry(a, c, 1u, c, 3u, hw, cursor, ent);
    }
    {   // t2: delta[c] += w*qa*qb ; delta[a] += w*qb*(qc-1) ; delta[b] += w*qa*(qc-1)
        int a = i2[3 * e], b = i2[3 * e + 1], c = i2[3 * e + 2];
        uint hw = (uint)__half_as_ushort(__float2half(w2[e]));
        put_entry(c, a, 0u, b, 0u, hw, cursor, ent);
        put_entry(a, b, 0u, c, 1u, hw, cursor, ent);
        put_entry(b, a, 0u, c, 1u, hw, cursor, ent);
    }
    {   // t3: delta[c] += w*qa*(1-qb) ; delta[a] += w*(1-qb)*(qc-1) ; delta[b] += w*qa*(1-qc)
        int a = i3[3 * e], b = i3[3 * e + 1], c = i3[3 * e + 2];
        uint hw = (uint)__half_as_ushort(__float2half(w3[e]));
        put_entry(c, a, 0u, b, 2u, hw, cursor, ent);
        put_entry(a, b, 2u, c, 1u, hw, cursor, ent);
        put_entry(b, a, 0u, c, 2u, hw, cursor, ent);
    }
}

// ---------------- init / finish transposes ----------------

// ev [B][N] -> ev_nb [N][B] (f32); logits_nb = ev_nb (f32); q0 = sigmoid(ev) (fp16)
__global__ void cavi_init_tp(const float* __restrict__ ev, float* __restrict__ ev_nb,
                             float* __restrict__ logits_nb, __half* __restrict__ q0) {
    __shared__ float lds[64 * 17];
    int n0 = blockIdx.x * 64;   // NN % 64 == 0
    #pragma unroll
    for (int p = 0; p < 4; ++p) {
        int idx = p * 256 + threadIdx.x;     // b-major
        int b = idx >> 6, i = idx & 63;
        lds[i * 17 + b] = ev[b * NN + n0 + i];
    }
    __syncthreads();
    #pragma unroll
    for (int p = 0; p < 4; ++p) {
        int j = p * 256 + threadIdx.x;       // j = i*16 + b
        int i = j >> 4, b = j & 15;
        float v = lds[i * 17 + b];
        int o = n0 * B + j;
        ev_nb[o] = v;
        logits_nb[o] = v;
        q0[o] = __float2half(sigmoidf_(v));
    }
}

// q_nb [N][B] fp16 -> out [B][N] f32
__global__ void cavi_out_tp(const __half* __restrict__ q_nb, float* __restrict__ out) {
    __shared__ float lds[64 * 17];
    int n0 = blockIdx.x * 64;
    #pragma unroll
    for (int p = 0; p < 4; ++p) {
        int j = p * 256 + threadIdx.x;       // j = i*16 + b
        int i = j >> 4, b = j & 15;
        lds[i * 17 + b] = __half2float(q_nb[n0 * B + j]);
    }
    __syncthreads();
    #pragma unroll
    for (int p = 0; p < 4; ++p) {
        int idx = p * 256 + threadIdx.x;     // b-major
        int b = idx >> 6, i = idx & 63;
        out[b * NN + n0 + i] = lds[i * 17 + b];
    }
}

// ---------------- main fused iteration (block per bucket, LDS reduction) ----------------

__global__ __launch_bounds__(256) void cavi_main_bkt(
        const uint* __restrict__ cursor, const uint2* __restrict__ ent,
        const float* __restrict__ ev_nb, float* __restrict__ logits_nb,
        const __half* __restrict__ q_in, __half* __restrict__ q_out) {
    __shared__ float dlt[BS * 16];          // 4 KB
    int tid = threadIdx.x;
    #pragma unroll
    for (int i = tid; i < BS * 16; i += 256) dlt[i] = 0.0f;
    __syncthreads();

    uint bk = blockIdx.x;
    uint cnt = cursor[bk * 16];
    if (cnt > CAP) cnt = CAP;
    const uint2* eb = ent + (size_t)bk * CAP;

    int b = tid & 15, g = tid >> 4;         // 16 groups of 16 lanes
    // contiguous chunk per group -> sequential entry reads, unroll-mergeable
    uint per = (cnt + 15) >> 4;
    uint kb = (uint)g * per; if (kb > cnt) kb = cnt;
    uint ke = kb + per;      if (ke > cnt) ke = cnt;

    uint k = kb;
    for (; k + 4 <= ke; k += 4) {
        // batch-decode 4 entries, issue all 8 gathers before any use
        float x[4], y[4], w[4];
        int ld[4];
        uint md1[4], md2[4];
        #pragma unroll
        for (int u = 0; u < 4; ++u) {
            uint2 e = eb[k + u];
            int s1 = (int)(e.x & 0x3FFFFu);
            int s2 = (int)(((e.x >> 20) & 0xFFFu) | ((e.y & 0x3Fu) << 12));
            md1[u] = (e.x >> 18) & 3u;
            md2[u] = (e.y >> 6) & 3u;
            ld[u] = (int)((e.y >> 8) & 0x3Fu);
            w[u] = __half2float(__ushort_as_half((ushort)(e.y >> 16)));
            x[u] = __half2float(q_in[(s1 << 4) + b]);
            y[u] = __half2float(q_in[(s2 << 4) + b]);
        }
        #pragma unroll
        for (int u = 0; u < 4; ++u) {
            float xv = (md1[u] == 0u) ? x[u] : ((md1[u] == 1u) ? x[u] - 1.0f : 1.0f - x[u]);
            float yv = (md2[u] == 0u) ? y[u]
                     : ((md2[u] == 1u) ? y[u] - 1.0f : ((md2[u] == 2u) ? 1.0f - y[u] : 1.0f));
            atomicAdd(&dlt[(ld[u] << 4) + b], w[u] * xv * yv);
        }
    }
    for (; k < ke; ++k) {
        uint2 e = eb[k];
        int s1 = (int)(e.x & 0x3FFFFu);
        int s2 = (int)(((e.x >> 20) & 0xFFFu) | ((e.y & 0x3Fu) << 12));
        uint m1 = (e.x >> 18) & 3u;
        uint m2 = (e.y >> 6) & 3u;
        int ld = (int)((e.y >> 8) & 0x3Fu);
        float w = __half2float(__ushort_as_half((ushort)(e.y >> 16)));
        float xv = __half2float(q_in[(s1 << 4) + b]);
        xv = (m1 == 0u) ? xv : ((m1 == 1u) ? xv - 1.0f : 1.0f - xv);
        float yv = __half2float(q_in[(s2 << 4) + b]);
        yv = (m2 == 0u) ? yv : ((m2 == 1u) ? yv - 1.0f : ((m2 == 2u) ? 1.0f - yv : 1.0f));
        atomicAdd(&dlt[(ld << 4) + b], w * xv * yv);
    }
    __syncthreads();

    int t0 = (int)bk * (BS * 16);
    #pragma unroll
    for (int i = tid; i < BS * 16; i += 256) {
        int t = t0 + i;
        float nl = 0.5f * logits_nb[t] + 0.5f * (ev_nb[t] + dlt[i]);
        logits_nb[t] = nl;
        q_out[t] = __float2half(sigmoidf_(nl));
    }
}

// ---------------- fallback (round-1 atomic path) ----------------

__global__ void fb_init(const float* __restrict__ ev, float* __restrict__ logits,
                        float* __restrict__ q_nb, float* __restrict__ delta_nb) {
    int i = blockIdx.x * blockDim.x + threadIdx.x;
    if (i >= NN * B) return;
    int b = i & 15, n = i >> 4;
    float e = ev[b * NN + n];
    logits[b * NN + n] = e;
    q_nb[i] = sigmoidf_(e);
    delta_nb[i] = 0.0f;
}

__global__ void fb_edges(const float* __restrict__ q, float* __restrict__ delta,
                         const int* __restrict__ idx1, const float* __restrict__ w1,
                         const int* __restrict__ idx2, const float* __restrict__ w2,
                         const int* __restrict__ idx3, const float* __restrict__ w3) {
    int gid = blockIdx.x * blockDim.x + threadIdx.x;
    int b = gid & 15;
    int e = gid >> 4;
    if (e >= 3 * R) return;
    if (e < R) {
        int a = idx1[e * 2 + 0], c = idx1[e * 2 + 1];
        float w = w1[e];
        float qa = q[a * B + b], qc = q[c * B + b];
        atomicAdd(&delta[c * B + b], w * qa);
        atomicAdd(&delta[a * B + b], w * (qc - 1.0f));
    } else if (e < 2 * R) {
        int ei = e - R;
        int a = idx2[ei * 3], bb = idx2[ei * 3 + 1], c = idx2[ei * 3 + 2];
        float w = w2[ei];
        float qa = q[a * B + b], qb = q[bb * B + b], qc = q[c * B + b];
        atomicAdd(&delta[c * B + b], w * qa * qb);
        atomicAdd(&delta[a * B + b], w * qb * (qc - 1.0f));
        atomicAdd(&delta[bb * B + b], w * qa * (qc - 1.0f));
    } else {
        int ei = e - 2 * R;
        int a = idx3[ei * 3], bb = idx3[ei * 3 + 1], c = idx3[ei * 3 + 2];
        float w = w3[ei];
        float qa = q[a * B + b], qb = q[bb * B + b], qc = q[c * B + b];
        atomicAdd(&delta[c * B + b], w * qa * (1.0f - qb));
        atomicAdd(&delta[a * B + b], w * (1.0f - qb) * (qc - 1.0f));
        atomicAdd(&delta[bb * B + b], w * qa * (1.0f - qc));
    }
}

__global__ void fb_update(const float* __restrict__ ev, float* __restrict__ logits,
                          float* __restrict__ q_nb, float* __restrict__ delta_nb, int write_q) {
    int i = blockIdx.x * blockDim.x + threadIdx.x;
    if (i >= NN * B) return;
    int b = i & 15, n = i >> 4;
    float d = delta_nb[i];
    delta_nb[i] = 0.0f;
    float e = ev[b * NN + n];
    float cl = logits[b * NN + n];
    float nl = 0.5f * cl + 0.5f * (e + d);
    float qv = sigmoidf_(nl);
    q_nb[i] = qv;
    logits[b * NN + n] = write_q ? qv : nl;
}

// ---------------- launch ----------------

extern "C" void kernel_launch(void* const* d_in, const int* in_sizes, int n_in,
                              void* d_out, int out_size, void* d_ws, size_t ws_size,
                              hipStream_t stream) {
    const float* ev = (const float*)d_in[0];
    const float* w1 = (const float*)d_in[1];
    const float* w2 = (const float*)d_in[2];
    const float* w3 = (const float*)d_in[3];
    const int* i1 = (const int*)d_in[4];
    const int* i2 = (const int*)d_in[5];
    const int* i3 = (const int*)d_in[6];

    const size_t NB = (size_t)NN * B;

    // workspace layout
    uint2* ent = (uint2*)d_ws;                           // NBUCK*CAP*8 = 89.6 MB
    float* ev_nb = (float*)(ent + (size_t)NBUCK * CAP);  // 12.8 MB
    float* logits_nb = ev_nb + NB;                       // 12.8 MB
    __half* q0 = (__half*)(logits_nb + NB);              // 6.4 MB
    __half* q1 = q0 + NB;                                // 6.4 MB
    uint* cursor = (uint*)(q1 + NB);                     // NBUCK*16 u32 = 200 KB
    size_t needed = (size_t)((char*)(cursor + NBUCK * 16) - (char*)d_ws);

    if (ws_size < needed) {
        // fallback: atomic path (needs 2*NB floats)
        float* logits = (float*)d_out;
        float* q_nb = (float*)d_ws;
        float* delta_nb = q_nb + NB;
        const int th = 256;
        const int nbg = (int)((NB + th - 1) / th);
        const int eg = (3 * R * B + th - 1) / th;
        fb_init<<<nbg, th, 0, stream>>>(ev, logits, q_nb, delta_nb);
        for (int it = 0; it < ITERS; ++it) {
            fb_edges<<<eg, th, 0, stream>>>(q_nb, delta_nb, i1, w1, i2, w2, i3, w3);
            fb_update<<<nbg, th, 0, stream>>>(ev, logits, q_nb, delta_nb, it == ITERS - 1 ? 1 : 0);
        }
        return;
    }

    const int th = 256;

    cavi_zero_cur<<<(NBUCK * 16 + th - 1) / th, th, 0, stream>>>(cursor);
    cavi_fill_bkt<<<(R + th - 1) / th, th, 0, stream>>>(i1, w1, i2, w2, i3, w3, cursor, ent);
    cavi_init_tp<<<NN / 64, 256, 0, stream>>>(ev, ev_nb, logits_nb, q0);

    __half* qi = q0;
    __half* qo = q1;
    for (int it = 0; it < ITERS; ++it) {
        cavi_main_bkt<<<NBUCK, 256, 0, stream>>>(cursor, ent, ev_nb, logits_nb, qi, qo);
        __half* tmp = qi; qi = qo; qo = tmp;
    }

    cavi_out_tp<<<NN / 64, 256, 0, stream>>>(qi, (float*)d_out);
}

// Round 7
// 3919.584 us; speedup vs baseline: 1.0645x; 1.0297x over previous
//
#include <hip/hip_runtime.h>
#include <hip/hip_fp16.h>

#define B 16
#define NN 200000
#define R 1000000
#define ITERS 5
#define NBUCK 3125            // NN / 64
#define BS 64                 // nodes per bucket
#define NSUB 8                // sub-lists per bucket (~per-XCD under round-robin dispatch)
#define SCAP 448              // capacity per (bucket, sub): mean 320, sigma ~18

typedef unsigned int uint;
typedef unsigned short ushort;
typedef unsigned long long ull;

__device__ __forceinline__ float sigmoidf_(float x) {
    return 1.0f / (1.0f + __expf(-x));
}

// ---------------- build phase (bucket scatter, XCD-class sub-lists) ----------------

__global__ void cavi_zero_cur(uint* __restrict__ cur) {
    int i = blockIdx.x * blockDim.x + threadIdx.x;
    if (i < NBUCK * NSUB) cur[i] = 0u;
}

// Entry (8B): lo = s1(0..17) | md1(18..19) | s2_lo12(20..31)
//             hi = s2_hi6(0..5) | md2(6..7) | ldest(8..13) | fp16 w(16..31)
// mods: 0 -> x, 1 -> x-1, 2 -> 1-x, 3 -> constant 1
__device__ __forceinline__ void put_entry(int dest, int s1, uint md1, int s2, uint md2,
                                          uint hw, uint sub, uint* __restrict__ cursor,
                                          uint2* __restrict__ ent) {
    uint bk = (uint)dest >> 6;
    uint ld = (uint)dest & 63u;
    uint cell = bk * NSUB + sub;
    uint pos = atomicAdd(&cursor[cell], 1u);
    if (pos < SCAP) {
        uint lo = (uint)s1 | (md1 << 18) | (((uint)s2 & 0xFFFu) << 20);
        uint hi = ((uint)s2 >> 12) | (md2 << 6) | (ld << 8) | (hw << 16);
        ent[(size_t)cell * SCAP + pos] = make_uint2(lo, hi);
    }
}

__global__ void cavi_fill_bkt(const int* __restrict__ i1, const float* __restrict__ w1,
                              const int* __restrict__ i2, const float* __restrict__ w2,
                              const int* __restrict__ i3, const float* __restrict__ w3,
                              uint* __restrict__ cursor, uint2* __restrict__ ent) {
    int e = blockIdx.x * blockDim.x + threadIdx.x;
    if (e >= R) return;
    uint sub = (uint)(blockIdx.x & (NSUB - 1));   // blocks of one class co-locate on an XCD
    {   // t1: delta[c] += w*qa ; delta[a] += w*(qc-1)   (s2=s1 line for the dead gather)
        int a = i1[2 * e], c = i1[2 * e + 1];
        uint hw = (uint)__half_as_ushort(__float2half(w1[e]));
        put_entry(c, a, 0u, a, 3u, hw, sub, cursor, ent);
        put_entry(a, c, 1u, c, 3u, hw, sub, cursor, ent);
    }
    {   // t2: delta[c] += w*qa*qb ; delta[a] += w*qb*(qc-1) ; delta[b] += w*qa*(qc-1)
        int a = i2[3 * e], b = i2[3 * e + 1], c = i2[3 * e + 2];
        uint hw = (uint)__half_as_ushort(__float2half(w2[e]));
        put_entry(c, a, 0u, b, 0u, hw, sub, cursor, ent);
        put_entry(a, b, 0u, c, 1u, hw, sub, cursor, ent);
        put_entry(b, a, 0u, c, 1u, hw, sub, cursor, ent);
    }
    {   // t3: delta[c] += w*qa*(1-qb) ; delta[a] += w*(1-qb)*(qc-1) ; delta[b] += w*qa*(1-qc)
        int a = i3[3 * e], b = i3[3 * e + 1], c = i3[3 * e + 2];
        uint hw = (uint)__half_as_ushort(__float2half(w3[e]));
        put_entry(c, a, 0u, b, 2u, hw, sub, cursor, ent);
        put_entry(a, b, 2u, c, 1u, hw, sub, cursor, ent);
        put_entry(b, a, 0u, c, 2u, hw, sub, cursor, ent);
    }
}

// ---------------- init / finish transposes (batch-halved layout) ----------------

// ev [B][N] -> per-half [N][8] f32 ev/logits, fp16 q0
__global__ void cavi_init_tp(const float* __restrict__ ev,
                             float* __restrict__ evh0, float* __restrict__ evh1,
                             float* __restrict__ lgh0, float* __restrict__ lgh1,
                             __half* __restrict__ qh0, __half* __restrict__ qh1) {
    __shared__ float lds[64 * 17];
    int n0 = blockIdx.x * 64;   // NN % 64 == 0
    #pragma unroll
    for (int p = 0; p < 4; ++p) {
        int idx = p * 256 + threadIdx.x;     // b-major
        int b = idx >> 6, i = idx & 63;
        lds[i * 17 + b] = ev[b * NN + n0 + i];
    }
    __syncthreads();
    #pragma unroll
    for (int p = 0; p < 2; ++p) {
        int j = p * 256 + threadIdx.x;       // j = i*8 + b, 512 per half
        int i = j >> 3, b = j & 7;
        int o = (n0 + i) * 8 + b;
        float v0 = lds[i * 17 + b];
        float v1 = lds[i * 17 + 8 + b];
        evh0[o] = v0; lgh0[o] = v0; qh0[o] = __float2half(sigmoidf_(v0));
        evh1[o] = v1; lgh1[o] = v1; qh1[o] = __float2half(sigmoidf_(v1));
    }
}

// final q halves [N][8] fp16 -> out [B][N] f32
__global__ void cavi_out_tp(const __half* __restrict__ qh0, const __half* __restrict__ qh1,
                            float* __restrict__ out) {
    __shared__ float lds[64 * 17];
    int n0 = blockIdx.x * 64;
    #pragma unroll
    for (int p = 0; p < 2; ++p) {
        int j = p * 256 + threadIdx.x;
        int i = j >> 3, b = j & 7;
        int o = (n0 + i) * 8 + b;
        lds[i * 17 + b]     = __half2float(qh0[o]);
        lds[i * 17 + 8 + b] = __half2float(qh1[o]);
    }
    __syncthreads();
    #pragma unroll
    for (int p = 0; p < 4; ++p) {
        int idx = p * 256 + threadIdx.x;
        int b = idx >> 6, i = idx & 63;
        out[b * NN + n0 + i] = lds[i * 17 + b];
    }
}

// ---------------- main fused iteration (block per bucket, one batch-half) ----------------

__global__ __launch_bounds__(256) void cavi_main_h(
        const uint* __restrict__ cursor, const uint2* __restrict__ ent,
        const float* __restrict__ evh, float* __restrict__ lgh,
        const __half* __restrict__ qih, __half* __restrict__ qoh) {
    __shared__ float dlt[BS * 8];           // 2 KB
    int tid = threadIdx.x;
    #pragma unroll
    for (int i = tid; i < BS * 8; i += 256) dlt[i] = 0.0f;
    __syncthreads();

    uint bk = blockIdx.x;
    int b = tid & 7, g = tid >> 3;          // 32 groups of 8 lanes
    int s = g >> 2, j = g & 3;              // 4 groups per sub-list
    uint cell = bk * NSUB + (uint)s;
    uint cnt = cursor[cell];
    if (cnt > SCAP) cnt = SCAP;
    const ull* eb = (const ull*)(ent + (size_t)cell * SCAP);

    uint per = (cnt + 3) >> 2;
    uint kb = (uint)j * per; if (kb > cnt) kb = cnt;
    uint ke = kb + per;      if (ke > cnt) ke = cnt;

    uint k = kb;
    for (; k + 4 <= ke; k += 4) {
        float x[4], y[4], w[4];
        int ld[4];
        uint md1[4], md2[4];
        #pragma unroll
        for (int u = 0; u < 4; ++u) {
            ull e = __builtin_nontemporal_load(&eb[k + u]);
            uint lo = (uint)e, hi = (uint)(e >> 32);
            int s1 = (int)(lo & 0x3FFFFu);
            int s2 = (int)(((lo >> 20) & 0xFFFu) | ((hi & 0x3Fu) << 12));
            md1[u] = (lo >> 18) & 3u;
            md2[u] = (hi >> 6) & 3u;
            ld[u] = (int)((hi >> 8) & 0x3Fu);
            w[u] = __half2float(__ushort_as_half((ushort)(hi >> 16)));
            x[u] = __half2float(qih[(s1 << 3) + b]);   // L2-resident (3.2 MB half)
            y[u] = __half2float(qih[(s2 << 3) + b]);
        }
        #pragma unroll
        for (int u = 0; u < 4; ++u) {
            float xv = (md1[u] == 0u) ? x[u] : ((md1[u] == 1u) ? x[u] - 1.0f : 1.0f - x[u]);
            float yv = (md2[u] == 0u) ? y[u]
                     : ((md2[u] == 1u) ? y[u] - 1.0f : ((md2[u] == 2u) ? 1.0f - y[u] : 1.0f));
            atomicAdd(&dlt[(ld[u] << 3) + b], w[u] * xv * yv);
        }
    }
    for (; k < ke; ++k) {
        ull e = __builtin_nontemporal_load(&eb[k]);
        uint lo = (uint)e, hi = (uint)(e >> 32);
        int s1 = (int)(lo & 0x3FFFFu);
        int s2 = (int)(((lo >> 20) & 0xFFFu) | ((hi & 0x3Fu) << 12));
        uint m1 = (lo >> 18) & 3u;
        uint m2 = (hi >> 6) & 3u;
        int ld = (int)((hi >> 8) & 0x3Fu);
        float w = __half2float(__ushort_as_half((ushort)(hi >> 16)));
        float xv = __half2float(qih[(s1 << 3) + b]);
        xv = (m1 == 0u) ? xv : ((m1 == 1u) ? xv - 1.0f : 1.0f - xv);
        float yv = __half2float(qih[(s2 << 3) + b]);
        yv = (m2 == 0u) ? yv : ((m2 == 1u) ? yv - 1.0f : ((m2 == 2u) ? 1.0f - yv : 1.0f));
        atomicAdd(&dlt[(ld << 3) + b], w * xv * yv);
    }
    __syncthreads();

    int t0 = (int)bk * (BS * 8);
    ushort* qoh_u = (ushort*)qoh;
    #pragma unroll
    for (int i = tid; i < BS * 8; i += 256) {
        int t = t0 + i;
        float cl = __builtin_nontemporal_load(&lgh[t]);
        float e  = __builtin_nontemporal_load(&evh[t]);
        float nl = 0.5f * cl + 0.5f * (e + dlt[i]);
        __builtin_nontemporal_store(nl, &lgh[t]);
        ushort qv = __half_as_ushort(__float2half(sigmoidf_(nl)));
        __builtin_nontemporal_store(qv, &qoh_u[t]);
    }
}

// ---------------- fallback (round-1 atomic path) ----------------

__global__ void fb_init(const float* __restrict__ ev, float* __restrict__ logits,
                        float* __restrict__ q_nb, float* __restrict__ delta_nb) {
    int i = blockIdx.x * blockDim.x + threadIdx.x;
    if (i >= NN * B) return;
    int b = i & 15, n = i >> 4;
    float e = ev[b * NN + n];
    logits[b * NN + n] = e;
    q_nb[i] = sigmoidf_(e);
    delta_nb[i] = 0.0f;
}

__global__ void fb_edges(const float* __restrict__ q, float* __restrict__ delta,
                         const int* __restrict__ idx1, const float* __restrict__ w1,
                         const int* __restrict__ idx2, const float* __restrict__ w2,
                         const int* __restrict__ idx3, const float* __restrict__ w3) {
    int gid = blockIdx.x * blockDim.x + threadIdx.x;
    int b = gid & 15;
    int e = gid >> 4;
    if (e >= 3 * R) return;
    if (e < R) {
        int a = idx1[e * 2 + 0], c = idx1[e * 2 + 1];
        float w = w1[e];
        float qa = q[a * B + b], qc = q[c * B + b];
        atomicAdd(&delta[c * B + b], w * qa);
        atomicAdd(&delta[a * B + b], w * (qc - 1.0f));
    } else if (e < 2 * R) {
        int ei = e - R;
        int a = idx2[ei * 3], bb = idx2[ei * 3 + 1], c = idx2[ei * 3 + 2];
        float w = w2[ei];
        float qa = q[a * B + b], qb = q[bb * B + b], qc = q[c * B + b];
        atomicAdd(&delta[c * B + b], w * qa * qb);
        atomicAdd(&delta[a * B + b], w * qb * (qc - 1.0f));
        atomicAdd(&delta[bb * B + b], w * qa * (qc - 1.0f));
    } else {
        int ei = e - 2 * R;
        int a = idx3[ei * 3], bb = idx3[ei * 3 + 1], c = idx3[ei * 3 + 2];
        float w = w3[ei];
        float qa = q[a * B + b], qb = q[bb * B + b], qc = q[c * B + b];
        atomicAdd(&delta[c * B + b], w * qa * (1.0f - qb));
        atomicAdd(&delta[a * B + b], w * (1.0f - qb) * (qc - 1.0f));
        atomicAdd(&delta[bb * B + b], w * qa * (1.0f - qc));
    }
}

__global__ void fb_update(const float* __restrict__ ev, float* __restrict__ logits,
                          float* __restrict__ q_nb, float* __restrict__ delta_nb, int write_q) {
    int i = blockIdx.x * blockDim.x + threadIdx.x;
    if (i >= NN * B) return;
    int b = i & 15, n = i >> 4;
    float d = delta_nb[i];
    delta_nb[i] = 0.0f;
    float e = ev[b * NN + n];
    float cl = logits[b * NN + n];
    float nl = 0.5f * cl + 0.5f * (e + d);
    float qv = sigmoidf_(nl);
    q_nb[i] = qv;
    logits[b * NN + n] = write_q ? qv : nl;
}

// ---------------- launch ----------------

extern "C" void kernel_launch(void* const* d_in, const int* in_sizes, int n_in,
                              void* d_out, int out_size, void* d_ws, size_t ws_size,
                              hipStream_t stream) {
    const float* ev = (const float*)d_in[0];
    const float* w1 = (const float*)d_in[1];
    const float* w2 = (const float*)d_in[2];
    const float* w3 = (const float*)d_in[3];
    const int* i1 = (const int*)d_in[4];
    const int* i2 = (const int*)d_in[5];
    const int* i3 = (const int*)d_in[6];

    const size_t NB = (size_t)NN * B;
    const size_t NH = (size_t)NN * 8;

    // workspace layout
    uint2* ent = (uint2*)d_ws;                               // 3125*8*448*8 = 89.6 MB
    float* evh0 = (float*)(ent + (size_t)NBUCK * NSUB * SCAP);
    float* evh1 = evh0 + NH;
    float* lgh0 = evh1 + NH;
    float* lgh1 = lgh0 + NH;
    __half* qA0 = (__half*)(lgh1 + NH);
    __half* qA1 = qA0 + NH;
    __half* qB0 = qA1 + NH;
    __half* qB1 = qB0 + NH;
    uint* cursor = (uint*)(qB1 + NH);                        // 25000 u32
    size_t needed = (size_t)((char*)(cursor + NBUCK * NSUB) - (char*)d_ws);

    if (ws_size < needed) {
        // fallback: atomic path (needs 2*NB floats)
        float* logits = (float*)d_out;
        float* q_nb = (float*)d_ws;
        float* delta_nb = q_nb + NB;
        const int th = 256;
        const int nbg = (int)((NB + th - 1) / th);
        const int eg = (3 * R * B + th - 1) / th;
        fb_init<<<nbg, th, 0, stream>>>(ev, logits, q_nb, delta_nb);
        for (int it = 0; it < ITERS; ++it) {
            fb_edges<<<eg, th, 0, stream>>>(q_nb, delta_nb, i1, w1, i2, w2, i3, w3);
            fb_update<<<nbg, th, 0, stream>>>(ev, logits, q_nb, delta_nb, it == ITERS - 1 ? 1 : 0);
        }
        return;
    }

    const int th = 256;

    cavi_zero_cur<<<(NBUCK * NSUB + th - 1) / th, th, 0, stream>>>(cursor);
    cavi_fill_bkt<<<(R + th - 1) / th, th, 0, stream>>>(i1, w1, i2, w2, i3, w3, cursor, ent);
    cavi_init_tp<<<NN / 64, 256, 0, stream>>>(ev, evh0, evh1, lgh0, lgh1, qA0, qA1);

    __half *qi0 = qA0, *qi1 = qA1, *qo0 = qB0, *qo1 = qB1;
    for (int it = 0; it < ITERS; ++it) {
        cavi_main_h<<<NBUCK, 256, 0, stream>>>(cursor, ent, evh0, lgh0, qi0, qo0);
        cavi_main_h<<<NBUCK, 256, 0, stream>>>(cursor, ent, evh1, lgh1, qi1, qo1);
        __half* t;
        t = qi0; qi0 = qo0; qo0 = t;
        t = qi1; qi1 = qo1; qo1 = t;
    }

    cavi_out_tp<<<NN / 64, 256, 0, stream>>>(qi0, qi1, (float*)d_out);
}

// Round 8
// 3892.781 us; speedup vs baseline: 1.0718x; 1.0069x over previous
//
#include <hip/hip_runtime.h>
#include <hip/hip_fp16.h>

#define B 16
#define NN 200000
#define R 1000000
#define ITERS 5
#define NBUCK 3125            // NN / 64
#define BS 64                 // nodes per bucket
#define NSUB 8                // sub-lists per bucket (~per-XCD under round-robin dispatch)
#define SCAP 448              // capacity per (bucket, sub): mean 320, sigma ~18
#define DSTRIDE 9             // padded LDS stride (floats) for delta[64][8]

typedef unsigned int uint;
typedef unsigned short ushort;
typedef unsigned long long ull;

__device__ __forceinline__ float sigmoidf_(float x) {
    return 1.0f / (1.0f + __expf(-x));
}

// ---------------- build phase (bucket scatter, XCD-class sub-lists) ----------------

__global__ void cavi_zero_cur(uint* __restrict__ cur) {
    int i = blockIdx.x * blockDim.x + threadIdx.x;
    if (i < NBUCK * NSUB) cur[i] = 0u;
}

// Entry (8B): lo = s1(0..17) | md1(18..19) | s2_lo12(20..31)
//             hi = s2_hi6(0..5) | md2(6..7) | ldest(8..13) | fp16 w(16..31)
// mods: 0 -> x, 1 -> x-1, 2 -> 1-x, 3 -> constant 1
__device__ __forceinline__ void put_entry(int dest, int s1, uint md1, int s2, uint md2,
                                          uint hw, uint sub, uint* __restrict__ cursor,
                                          uint2* __restrict__ ent) {
    uint bk = (uint)dest >> 6;
    uint ld = (uint)dest & 63u;
    uint cell = bk * NSUB + sub;
    uint pos = atomicAdd(&cursor[cell], 1u);
    if (pos < SCAP) {
        uint lo = (uint)s1 | (md1 << 18) | (((uint)s2 & 0xFFFu) << 20);
        uint hi = ((uint)s2 >> 12) | (md2 << 6) | (ld << 8) | (hw << 16);
        ent[(size_t)cell * SCAP + pos] = make_uint2(lo, hi);
    }
}

__global__ void cavi_fill_bkt(const int* __restrict__ i1, const float* __restrict__ w1,
                              const int* __restrict__ i2, const float* __restrict__ w2,
                              const int* __restrict__ i3, const float* __restrict__ w3,
                              uint* __restrict__ cursor, uint2* __restrict__ ent) {
    int e = blockIdx.x * blockDim.x + threadIdx.x;
    if (e >= R) return;
    uint sub = (uint)(blockIdx.x & (NSUB - 1));   // blocks of one class co-locate on an XCD
    {   // t1: delta[c] += w*qa ; delta[a] += w*(qc-1)   (s2=s1 so the dead gather shares the line)
        int a = i1[2 * e], c = i1[2 * e + 1];
        uint hw = (uint)__half_as_ushort(__float2half(w1[e]));
        put_entry(c, a, 0u, a, 3u, hw, sub, cursor, ent);
        put_entry(a, c, 1u, c, 3u, hw, sub, cursor, ent);
    }
    {   // t2: delta[c] += w*qa*qb ; delta[a] += w*qb*(qc-1) ; delta[b] += w*qa*(qc-1)
        int a = i2[3 * e], b = i2[3 * e + 1], c = i2[3 * e + 2];
        uint hw = (uint)__half_as_ushort(__float2half(w2[e]));
        put_entry(c, a, 0u, b, 0u, hw, sub, cursor, ent);
        put_entry(a, b, 0u, c, 1u, hw, sub, cursor, ent);
        put_entry(b, a, 0u, c, 1u, hw, sub, cursor, ent);
    }
    {   // t3: delta[c] += w*qa*(1-qb) ; delta[a] += w*(1-qb)*(qc-1) ; delta[b] += w*qa*(1-qc)
        int a = i3[3 * e], b = i3[3 * e + 1], c = i3[3 * e + 2];
        uint hw = (uint)__half_as_ushort(__float2half(w3[e]));
        put_entry(c, a, 0u, b, 2u, hw, sub, cursor, ent);
        put_entry(a, b, 2u, c, 1u, hw, sub, cursor, ent);
        put_entry(b, a, 0u, c, 2u, hw, sub, cursor, ent);
    }
}

// ---------------- init / finish transposes (batch-halved layout) ----------------

// ev [B][N] -> per-half [N][8] f32 ev/logits, fp16 q0
__global__ void cavi_init_tp(const float* __restrict__ ev,
                             float* __restrict__ evh0, float* __restrict__ evh1,
                             float* __restrict__ lgh0, float* __restrict__ lgh1,
                             __half* __restrict__ qh0, __half* __restrict__ qh1) {
    __shared__ float lds[64 * 17];
    int n0 = blockIdx.x * 64;   // NN % 64 == 0
    #pragma unroll
    for (int p = 0; p < 4; ++p) {
        int idx = p * 256 + threadIdx.x;     // b-major
        int b = idx >> 6, i = idx & 63;
        lds[i * 17 + b] = ev[b * NN + n0 + i];
    }
    __syncthreads();
    #pragma unroll
    for (int p = 0; p < 2; ++p) {
        int j = p * 256 + threadIdx.x;       // j = i*8 + b, 512 per half
        int i = j >> 3, b = j & 7;
        int o = (n0 + i) * 8 + b;
        float v0 = lds[i * 17 + b];
        float v1 = lds[i * 17 + 8 + b];
        evh0[o] = v0; lgh0[o] = v0; qh0[o] = __float2half(sigmoidf_(v0));
        evh1[o] = v1; lgh1[o] = v1; qh1[o] = __float2half(sigmoidf_(v1));
    }
}

// final q halves [N][8] fp16 -> out [B][N] f32
__global__ void cavi_out_tp(const __half* __restrict__ qh0, const __half* __restrict__ qh1,
                            float* __restrict__ out) {
    __shared__ float lds[64 * 17];
    int n0 = blockIdx.x * 64;
    #pragma unroll
    for (int p = 0; p < 2; ++p) {
        int j = p * 256 + threadIdx.x;
        int i = j >> 3, b = j & 7;
        int o = (n0 + i) * 8 + b;
        lds[i * 17 + b]     = __half2float(qh0[o]);
        lds[i * 17 + 8 + b] = __half2float(qh1[o]);
    }
    __syncthreads();
    #pragma unroll
    for (int p = 0; p < 4; ++p) {
        int idx = p * 256 + threadIdx.x;
        int b = idx >> 6, i = idx & 63;
        out[b * NN + n0 + i] = lds[i * 17 + b];
    }
}

// ---------------- main fused iteration: ONE ENTRY PER LANE ----------------

__device__ __forceinline__ void unpack8(uint4 v, float* f) {
    const __half2* h = (const __half2*)&v;
    #pragma unroll
    for (int p = 0; p < 4; ++p) {
        float2 t = __half22float2(h[p]);
        f[2 * p]     = t.x;
        f[2 * p + 1] = t.y;
    }
}

__global__ __launch_bounds__(256) void cavi_main_h(
        const uint* __restrict__ cursor, const uint2* __restrict__ ent,
        const float* __restrict__ evh, float* __restrict__ lgh,
        const __half* __restrict__ qih, __half* __restrict__ qoh) {
    __shared__ float dlt[BS * DSTRIDE];     // 64*9*4 = 2304 B, stride-9 spreads banks
    int tid = threadIdx.x;
    for (int i = tid; i < BS * DSTRIDE; i += 256) dlt[i] = 0.0f;
    __syncthreads();

    uint bk = blockIdx.x;
    int s = tid >> 5;                       // sub-list 0..7
    int l = tid & 31;                       // lane within sub-list
    uint cell = bk * NSUB + (uint)s;
    uint cnt = cursor[cell];
    if (cnt > SCAP) cnt = SCAP;
    const ull* eb = (const ull*)(ent + (size_t)cell * SCAP);
    const uint4* q4 = (const uint4*)qih;    // 8 fp16 per node-half = 16 B

    for (uint k = (uint)l; k < cnt; k += 32) {
        ull e = __builtin_nontemporal_load(&eb[k]);   // coalesced 8B/lane; NT protects q in L2
        uint lo = (uint)e, hi = (uint)(e >> 32);
        int s1 = (int)(lo & 0x3FFFFu);
        int s2 = (int)(((lo >> 20) & 0xFFFu) | ((hi & 0x3Fu) << 12));
        uint md1 = (lo >> 18) & 3u;
        uint md2 = (hi >> 6) & 3u;
        int ld = (int)((hi >> 8) & 0x3Fu);
        float w = __half2float(__ushort_as_half((ushort)(hi >> 16)));
        // mod -> (sign, offset):  0:x=(1,0)  1:x-1=(1,-1)  2:1-x=(-1,1)  3:1=(0,1)
        float sg1 = (md1 == 2u) ? -1.0f : ((md1 == 3u) ? 0.0f : 1.0f);
        float of1 = (md1 == 0u) ? 0.0f : ((md1 == 1u) ? -1.0f : 1.0f);
        float sg2 = (md2 == 2u) ? -1.0f : ((md2 == 3u) ? 0.0f : 1.0f);
        float of2 = (md2 == 0u) ? 0.0f : ((md2 == 1u) ? -1.0f : 1.0f);

        uint4 xr = q4[s1];                  // per-lane 16B gather (8 batches)
        uint4 yr = q4[s2];
        float xf[8], yf[8];
        unpack8(xr, xf);
        unpack8(yr, yf);

        float* dp = &dlt[ld * DSTRIDE];
        #pragma unroll
        for (int bb = 0; bb < 8; ++bb) {
            float xm = fmaf(sg1, xf[bb], of1);
            float ym = fmaf(sg2, yf[bb], of2);
            atomicAdd(&dp[bb], w * xm * ym);
        }
    }
    __syncthreads();

    int t0 = (int)bk * (BS * 8);
    ushort* qoh_u = (ushort*)qoh;
    #pragma unroll
    for (int i = tid; i < BS * 8; i += 256) {
        int t = t0 + i;
        float cl = __builtin_nontemporal_load(&lgh[t]);
        float e  = __builtin_nontemporal_load(&evh[t]);
        float nl = 0.5f * cl + 0.5f * (e + dlt[(i >> 3) * DSTRIDE + (i & 7)]);
        __builtin_nontemporal_store(nl, &lgh[t]);
        // NORMAL store for q: next dispatch gathers it from L2
        qoh_u[t] = __half_as_ushort(__float2half(sigmoidf_(nl)));
    }
}

// ---------------- fallback (round-1 atomic path) ----------------

__global__ void fb_init(const float* __restrict__ ev, float* __restrict__ logits,
                        float* __restrict__ q_nb, float* __restrict__ delta_nb) {
    int i = blockIdx.x * blockDim.x + threadIdx.x;
    if (i >= NN * B) return;
    int b = i & 15, n = i >> 4;
    float e = ev[b * NN + n];
    logits[b * NN + n] = e;
    q_nb[i] = sigmoidf_(e);
    delta_nb[i] = 0.0f;
}

__global__ void fb_edges(const float* __restrict__ q, float* __restrict__ delta,
                         const int* __restrict__ idx1, const float* __restrict__ w1,
                         const int* __restrict__ idx2, const float* __restrict__ w2,
                         const int* __restrict__ idx3, const float* __restrict__ w3) {
    int gid = blockIdx.x * blockDim.x + threadIdx.x;
    int b = gid & 15;
    int e = gid >> 4;
    if (e >= 3 * R) return;
    if (e < R) {
        int a = idx1[e * 2 + 0], c = idx1[e * 2 + 1];
        float w = w1[e];
        float qa = q[a * B + b], qc = q[c * B + b];
        atomicAdd(&delta[c * B + b], w * qa);
        atomicAdd(&delta[a * B + b], w * (qc - 1.0f));
    } else if (e < 2 * R) {
        int ei = e - R;
        int a = idx2[ei * 3], bb = idx2[ei * 3 + 1], c = idx2[ei * 3 + 2];
        float w = w2[ei];
        float qa = q[a * B + b], qb = q[bb * B + b], qc = q[c * B + b];
        atomicAdd(&delta[c * B + b], w * qa * qb);
        atomicAdd(&delta[a * B + b], w * qb * (qc - 1.0f));
        atomicAdd(&delta[bb * B + b], w * qa * (qc - 1.0f));
    } else {
        int ei = e - 2 * R;
        int a = idx3[ei * 3], bb = idx3[ei * 3 + 1], c = idx3[ei * 3 + 2];
        float w = w3[ei];
        float qa = q[a * B + b], qb = q[bb * B + b], qc = q[c * B + b];
        atomicAdd(&delta[c * B + b], w * qa * (1.0f - qb));
        atomicAdd(&delta[a * B + b], w * (1.0f - qb) * (qc - 1.0f));
        atomicAdd(&delta[bb * B + b], w * qa * (1.0f - qc));
    }
}

__global__ void fb_update(const float* __restrict__ ev, float* __restrict__ logits,
                          float* __restrict__ q_nb, float* __restrict__ delta_nb, int write_q) {
    int i = blockIdx.x * blockDim.x + threadIdx.x;
    if (i >= NN * B) return;
    int b = i & 15, n = i >> 4;
    float d = delta_nb[i];
    delta_nb[i] = 0.0f;
    float e = ev[b * NN + n];
    float cl = logits[b * NN + n];
    float nl = 0.5f * cl + 0.5f * (e + d);
    float qv = sigmoidf_(nl);
    q_nb[i] = qv;
    logits[b * NN + n] = write_q ? qv : nl;
}

// ---------------- launch ----------------

extern "C" void kernel_launch(void* const* d_in, const int* in_sizes, int n_in,
                              void* d_out, int out_size, void* d_ws, size_t ws_size,
                              hipStream_t stream) {
    const float* ev = (const float*)d_in[0];
    const float* w1 = (const float*)d_in[1];
    const float* w2 = (const float*)d_in[2];
    const float* w3 = (const float*)d_in[3];
    const int* i1 = (const int*)d_in[4];
    const int* i2 = (const int*)d_in[5];
    const int* i3 = (const int*)d_in[6];

    const size_t NB = (size_t)NN * B;
    const size_t NH = (size_t)NN * 8;

    // workspace layout
    uint2* ent = (uint2*)d_ws;                               // 3125*8*448*8 = 89.6 MB
    float* evh0 = (float*)(ent + (size_t)NBUCK * NSUB * SCAP);
    float* evh1 = evh0 + NH;
    float* lgh0 = evh1 + NH;
    float* lgh1 = lgh0 + NH;
    __half* qA0 = (__half*)(lgh1 + NH);
    __half* qA1 = qA0 + NH;
    __half* qB0 = qA1 + NH;
    __half* qB1 = qB0 + NH;
    uint* cursor = (uint*)(qB1 + NH);                        // 25000 u32
    size_t needed = (size_t)((char*)(cursor + NBUCK * NSUB) - (char*)d_ws);

    if (ws_size < needed) {
        // fallback: atomic path (needs 2*NB floats)
        float* logits = (float*)d_out;
        float* q_nb = (float*)d_ws;
        float* delta_nb = q_nb + NB;
        const int th = 256;
        const int nbg = (int)((NB + th - 1) / th);
        const int eg = (3 * R * B + th - 1) / th;
        fb_init<<<nbg, th, 0, stream>>>(ev, logits, q_nb, delta_nb);
        for (int it = 0; it < ITERS; ++it) {
            fb_edges<<<eg, th, 0, stream>>>(q_nb, delta_nb, i1, w1, i2, w2, i3, w3);
            fb_update<<<nbg, th, 0, stream>>>(ev, logits, q_nb, delta_nb, it == ITERS - 1 ? 1 : 0);
        }
        return;
    }

    const int th = 256;

    cavi_zero_cur<<<(NBUCK * NSUB + th - 1) / th, th, 0, stream>>>(cursor);
    cavi_fill_bkt<<<(R + th - 1) / th, th, 0, stream>>>(i1, w1, i2, w2, i3, w3, cursor, ent);
    cavi_init_tp<<<NN / 64, 256, 0, stream>>>(ev, evh0, evh1, lgh0, lgh1, qA0, qA1);

    __half *qi0 = qA0, *qi1 = qA1, *qo0 = qB0, *qo1 = qB1;
    for (int it = 0; it < ITERS; ++it) {
        cavi_main_h<<<NBUCK, 256, 0, stream>>>(cursor, ent, evh0, lgh0, qi0, qo0);
        cavi_main_h<<<NBUCK, 256, 0, stream>>>(cursor, ent, evh1, lgh1, qi1, qo1);
        __half* t;
        t = qi0; qi0 = qo0; qo0 = t;
        t = qi1; qi1 = qo1; qo1 = t;
    }

    cavi_out_tp<<<NN / 64, 256, 0, stream>>>(qi0, qi1, (float*)d_out);
}